// Round 16
// baseline (554.762 us; speedup 1.0000x reference)
//
#include <hip/hip_runtime.h>
#include <hip/hip_fp16.h>
#include <math.h>

#define N_NODES    100000
#define N_EDGES    3200000
#define NUM_GRAPHS 512
#define D_IN       7
#define D_H        16
#define D_H2       8                           // half2 words per node row (16 feats)
#define SHIFT      7
#define BWIDTH     128                         // cols per bucket
#define NB         782                         // ceil(N_NODES / BWIDTH)
#define CHUNK      4096
#define NCH        782                         // ceil(N_EDGES / CHUNK)
#define TPH        36                          // words/feature-word row per half (32+4; %4==0)
#define HST        (8 * TPH)                   // 288 words per half (pull2, 8-word rows)
#define TP1        36
#define HST1       (4 * TP1)                   // 144 words per half (pull1, 4-word rows)

// ---- device-scope grid barrier (all blocks co-resident by construction) ----
__device__ __forceinline__ void gsync(int* ctr, int target) {
    __syncthreads();
    if (threadIdx.x == 0) {
        __threadfence();   // agent-scope release: writes back this XCD's L2
        __hip_atomic_fetch_add(ctr, 1, __ATOMIC_ACQ_REL, __HIP_MEMORY_SCOPE_AGENT);
        while (__hip_atomic_load(ctr, __ATOMIC_ACQUIRE, __HIP_MEMORY_SCOPE_AGENT) < target)
            __builtin_amdgcn_s_sleep(2);
        __threadfence();   // agent-scope acquire side: invalidate stale lines
    }
    __syncthreads();
}

// ---- ONE kernel: hist -> colscan -> scan -> place -> csr -> xs ----
// Phases are the proven R15 kernels, grid-strided. 44.3KB LDS, 512 threads.
__global__ void __launch_bounds__(512)
build_all(const int* __restrict__ row, const int* __restrict__ col,
          const float* __restrict__ x,
          int* __restrict__ cnt, int* __restrict__ base, int* __restrict__ bcnt,
          int* __restrict__ offs, int* __restrict__ part, int* __restrict__ csr,
          int* __restrict__ node_off, int* __restrict__ deg, float* __restrict__ dinv,
          unsigned* __restrict__ xsh, int* ctr, int nblk) {
    __shared__ int smem[11072];               // 44288 B
    int* lh    = smem;                        // 782
    int* sc    = smem + 782;                  // 782
    int* lb    = smem + 1564;                 // 782
    int* ts    = smem + 2346;                 // 512
    int* stage = smem + 2858;                 // 4096
    int* dstv  = smem + 6954;                 // 4096

    int bid = blockIdx.x;
    int tid = threadIdx.x;

    // ---- P1: per-chunk bucket histograms -> cnt[chunk][bucket] ----
    for (int c = bid; c < NCH; c += nblk) {
        for (int i = tid; i < NB; i += 512) lh[i] = 0;
        __syncthreads();
        int e0 = c * CHUNK;
        int n  = N_EDGES - e0; if (n > CHUNK) n = CHUNK;
        if (n == CHUNK) {
            const int4* cp = (const int4*)(col + e0);
#pragma unroll
            for (int q = 0; q < 2; ++q) {
                int4 v = cp[tid + q * 512];
                atomicAdd(&lh[v.x >> SHIFT], 1);
                atomicAdd(&lh[v.y >> SHIFT], 1);
                atomicAdd(&lh[v.z >> SHIFT], 1);
                atomicAdd(&lh[v.w >> SHIFT], 1);
            }
        } else {
            for (int e = tid; e < n; e += 512)
                atomicAdd(&lh[col[e0 + e] >> SHIFT], 1);
        }
        __syncthreads();
        int* op = cnt + (size_t)c * NB;
        for (int i = tid; i < NB; i += 512) op[i] = lh[i];
        __syncthreads();
    }
    gsync(ctr, nblk);

    // ---- P2: per-bucket exclusive scan over chunks -> base[bucket][chunk], bcnt ----
    for (int b = bid; b < NB; b += nblk) {
        int c0 = tid * 2;
        int v0 = (c0 < NCH)     ? cnt[(size_t)c0 * NB + b]       : 0;
        int v1 = (c0 + 1 < NCH) ? cnt[(size_t)(c0 + 1) * NB + b] : 0;
        int sum = v0 + v1;
        ts[tid] = sum;
        __syncthreads();
        for (int st = 1; st < 512; st <<= 1) {
            int v = (tid >= st) ? ts[tid - st] : 0;
            __syncthreads();
            ts[tid] += v;
            __syncthreads();
        }
        int run = ts[tid] - sum;
        int* bp = base + (size_t)b * NCH;
        if (c0 < NCH)     bp[c0]     = run;
        if (c0 + 1 < NCH) bp[c0 + 1] = run + v0;
        if (tid == 511) bcnt[b] = ts[511];
        __syncthreads();
    }
    gsync(ctr, 2 * nblk);

    // ---- P3: exclusive scan of bucket totals -> offs (block 0) ----
    if (bid == 0) {
        int i0 = 2 * tid;
        int s0 = (i0 < NB)     ? bcnt[i0]     : 0;
        int s1 = (i0 + 1 < NB) ? bcnt[i0 + 1] : 0;
        int ps = s0 + s1;
        ts[tid] = ps;
        __syncthreads();
        for (int st = 1; st < 512; st <<= 1) {
            int v = (tid >= st) ? ts[tid - st] : 0;
            __syncthreads();
            ts[tid] += v;
            __syncthreads();
        }
        int excl = ts[tid] - ps;
        if (i0 <= NB)     offs[i0]     = excl;
        if (i0 + 1 <= NB) offs[i0 + 1] = excl + s0;
    }
    gsync(ctr, 3 * nblk);

    // ---- P4: place (LDS counting sort + precomputed dst + coalesced flush) ----
    for (int c = bid; c < NCH; c += nblk) {
        int e0 = c * CHUNK;
        int e1 = e0 + CHUNK; if (e1 > N_EDGES) e1 = N_EDGES;
        int n  = e1 - e0;
        for (int i = tid; i < NB; i += 512) lh[i] = 0;
        __syncthreads();
        for (int e = e0 + tid; e < e1; e += 512)
            atomicAdd(&lh[col[e] >> SHIFT], 1);
        __syncthreads();
        int b0 = tid * 2;
        int va = (b0 < NB)     ? lh[b0]     : 0;
        int vb = (b0 + 1 < NB) ? lh[b0 + 1] : 0;
        int sum = va + vb;
        ts[tid] = sum;
        __syncthreads();
        for (int st = 1; st < 512; st <<= 1) {
            int v = (tid >= st) ? ts[tid - st] : 0;
            __syncthreads();
            ts[tid] += v;
            __syncthreads();
        }
        int run = ts[tid] - sum;
        if (b0 < NB) {
            sc[b0] = run;
            lb[b0] = offs[b0] + base[(size_t)b0 * NCH + c];
            lh[b0] = 0;
        }
        if (b0 + 1 < NB) {
            sc[b0 + 1] = run + va;
            lb[b0 + 1] = offs[b0 + 1] + base[(size_t)(b0 + 1) * NCH + c];
            lh[b0 + 1] = 0;
        }
        __syncthreads();
        for (int e = e0 + tid; e < e1; e += 512) {
            int cc = col[e];
            int b = cc >> SHIFT;
            int rank = atomicAdd(&lh[b], 1);
            int loc = sc[b] + rank;
            stage[loc] = (row[e] << SHIFT) | (cc & (BWIDTH - 1));
            dstv[loc]  = lb[b] + rank;
        }
        __syncthreads();
        for (int i = tid; i < n; i += 512)
            part[dstv[i]] = stage[i];
        __syncthreads();
    }
    gsync(ctr, 4 * nblk);

    // ---- P5: per-bucket CSR build + node_off/deg/dinv ----
    {
        int* cntb = smem;         // 128
        int* scnb = smem + 128;   // 128
        int* curb = smem + 256;   // 128
        for (int b = bid; b < NB; b += nblk) {
            int o0 = offs[b], o1 = offs[b + 1];
            if (tid < BWIDTH) cntb[tid] = 0;
            __syncthreads();
            for (int j = o0 + tid; j < o1; j += 512)
                atomicAdd(&cntb[part[j] & (BWIDTH - 1)], 1);
            __syncthreads();
            if (tid < BWIDTH) scnb[tid] = cntb[tid];
            __syncthreads();
            for (int st = 1; st < BWIDTH; st <<= 1) {
                int v = 0;
                if (tid < BWIDTH && tid >= st) v = scnb[tid - st];
                __syncthreads();
                if (tid < BWIDTH) scnb[tid] += v;
                __syncthreads();
            }
            if (tid < BWIDTH) {
                int excl = scnb[tid] - cntb[tid];
                curb[tid] = excl;
                int cnode = b * BWIDTH + tid;
                if (cnode < N_NODES) {
                    node_off[cnode] = o0 + excl;
                    deg[cnode] = cntb[tid];
                    dinv[cnode] = rsqrtf((float)cntb[tid] + 1.0f);  // +1 self-loop
                }
            }
            __syncthreads();
            for (int j = o0 + tid; j < o1; j += 512) {
                int e = part[j];
                int l = e & (BWIDTH - 1);
                int pos = atomicAdd(&curb[l], 1);
                csr[o0 + pos] = e >> SHIFT;
            }
            __syncthreads();
        }
    }
    gsync(ctr, 5 * nblk);

    // ---- P6: xs[v,:] = dinv[v]*x[v,:], packed 8 halves (7 feats + pad) ----
    for (int v = bid * 512 + tid; v < N_NODES; v += nblk * 512) {
        float dv = dinv[v];
        float xv[8];
#pragma unroll
        for (int j = 0; j < D_IN; ++j) xv[j] = x[v * D_IN + j] * dv;
        xv[7] = 0.f;
#pragma unroll
        for (int w = 0; w < 4; ++w) {
            __half2 p = __floats2half2_rn(xv[2 * w], xv[2 * w + 1]);
            xsh[(size_t)v * 4 + w] = *(unsigned*)&p;
        }
    }
}

// ---- pull1: 2 nodes/wave, 16B x-rows, post-aggregation @W1 then @W2 (R15) ----
__global__ void __launch_bounds__(256, 8)
pull1_kernel(const unsigned* __restrict__ xsh, const int* __restrict__ csr,
             const int* __restrict__ node_off, const int* __restrict__ deg,
             const float* __restrict__ dinv, const float* __restrict__ b1,
             const float* __restrict__ W1, const float* __restrict__ W2,
             unsigned* __restrict__ s2h) {
    __shared__ unsigned stage[4][2 * HST1];   // 4608 B
    __shared__ float aggrow[4][2][8];
    __shared__ float hrow[4][2][D_H];
    int wave = threadIdx.x >> 6;
    int lane = threadIdx.x & 63;
    int h = lane >> 5, l = lane & 31;
    int v = blockIdx.x * 8 + wave * 2 + h;
    int k = l & 15;
    float w1c[D_IN];
#pragma unroll
    for (int j = 0; j < D_IN; ++j) w1c[j] = W1[j * D_H + k];
    float w2c[D_H];
#pragma unroll
    for (int j = 0; j < D_H; ++j) w2c[j] = W2[j * D_H + k];
    int d = deg[v], o0 = node_off[v];
    unsigned* stg = stage[wave] + h * HST1;
    int rg = l >> 3, p = l & 7;
    int w = p >> 1;
    bool hi = (p & 1);
    const uint4* rp = (const uint4*)(stg + w * TP1 + rg * 8);
    float acc = 0.f;
    for (int base = 0; base < d; base += 32) {
        int j = base + l;
        uint4 a = make_uint4(0u, 0u, 0u, 0u);
        if (j < d) {
            int r = __builtin_nontemporal_load(&csr[o0 + j]);
            a = *(const uint4*)(xsh + (size_t)r * 4);
        }
        asm volatile("s_waitcnt lgkmcnt(0)" ::: "memory");
        stg[0 * TP1 + l] = a.x;
        stg[1 * TP1 + l] = a.y;
        stg[2 * TP1 + l] = a.z;
        stg[3 * TP1 + l] = a.w;
        asm volatile("s_waitcnt lgkmcnt(0)" ::: "memory");
        uint4 q0 = rp[0], q1 = rp[1];
        unsigned ws[8] = { q0.x, q0.y, q0.z, q0.w, q1.x, q1.y, q1.z, q1.w };
#pragma unroll
        for (int i = 0; i < 8; ++i) {
            __half2 ph = *(__half2*)&ws[i];
            acc += hi ? __high2float(ph) : __low2float(ph);
        }
    }
    acc += __shfl_xor(acc, 8, 64);
    acc += __shfl_xor(acc, 16, 64);   // all 32 lanes: agg for x-feature p
    float dv = dinv[v];
    if (l < 8) aggrow[wave][h][l] = acc;
    asm volatile("s_waitcnt lgkmcnt(0)" ::: "memory");
    uint4 sx = *(const uint4*)(xsh + (size_t)v * 4);
    unsigned sxw[4] = { sx.x, sx.y, sx.z, sx.w };
    const float* ag = aggrow[wave][h];
    float hv = b1[k];
#pragma unroll
    for (int j = 0; j < D_IN; ++j) {
        __half2 ph = *(__half2*)&sxw[j >> 1];
        float xsv = (j & 1) ? __high2float(ph) : __low2float(ph);
        hv += dv * (ag[j] + xsv) * w1c[j];
    }
    hv = fmaxf(hv, 0.f);
    if (l < 16) hrow[wave][h][k] = hv;
    asm volatile("s_waitcnt lgkmcnt(0)" ::: "memory");
    const float4* hp = (const float4*)hrow[wave][h];
    float4 h0 = hp[0], h1 = hp[1], h2 = hp[2], h3 = hp[3];
    float a2 = h0.x * w2c[0] + h0.y * w2c[1] + h0.z * w2c[2] + h0.w * w2c[3]
             + h1.x * w2c[4] + h1.y * w2c[5] + h1.z * w2c[6] + h1.w * w2c[7]
             + h2.x * w2c[8] + h2.y * w2c[9] + h2.z * w2c[10] + h2.w * w2c[11]
             + h3.x * w2c[12] + h3.y * w2c[13] + h3.z * w2c[14] + h3.w * w2c[15];
    a2 *= dv;
    float a2hi = __shfl_xor(a2, 1, 64);
    if (l < 16 && (k & 1) == 0) {
        __half2 pq = __floats2half2_rn(a2, a2hi);
        s2h[(size_t)v * D_H2 + (k >> 1)] = *(unsigned*)&pq;
    }
}

// ---- pull2 gather core (R14): 2 nodes/wave, 32B s2-rows ----
__device__ __forceinline__ float gather_half(const unsigned* __restrict__ sh,
                                             const int* __restrict__ csr,
                                             int o0, int d, unsigned* stg, int l) {
    int g = l >> 4, k = l & 15;
    const uint4* rp = (const uint4*)(stg + (k >> 1) * TPH + g * 16);
    bool hi = (k & 1);
    float acc = 0.f;
    for (int base = 0; base < d; base += 32) {
        int j = base + l;
        uint4 a = make_uint4(0u, 0u, 0u, 0u), b = make_uint4(0u, 0u, 0u, 0u);
        if (j < d) {
            int r = __builtin_nontemporal_load(&csr[o0 + j]);
            const uint4* sp = (const uint4*)(sh + (size_t)r * D_H2);
            a = sp[0];
            b = sp[1];
        }
        asm volatile("s_waitcnt lgkmcnt(0)" ::: "memory");
        stg[0 * TPH + l] = a.x;
        stg[1 * TPH + l] = a.y;
        stg[2 * TPH + l] = a.z;
        stg[3 * TPH + l] = a.w;
        stg[4 * TPH + l] = b.x;
        stg[5 * TPH + l] = b.y;
        stg[6 * TPH + l] = b.z;
        stg[7 * TPH + l] = b.w;
        asm volatile("s_waitcnt lgkmcnt(0)" ::: "memory");
        uint4 q0 = rp[0], q1 = rp[1], q2 = rp[2], q3 = rp[3];
        unsigned ws[16] = { q0.x, q0.y, q0.z, q0.w, q1.x, q1.y, q1.z, q1.w,
                            q2.x, q2.y, q2.z, q2.w, q3.x, q3.y, q3.z, q3.w };
#pragma unroll
        for (int i = 0; i < 16; ++i) {
            __half2 p = *(__half2*)&ws[i];
            acc += hi ? __high2float(p) : __low2float(p);
        }
    }
    acc += __shfl_xor(acc, 16, 64);
    return acc;
}

// layer-2 pull (2 nodes/wave): h2 = relu(dinv*(gather+self)+b2), fp32 out
__global__ void __launch_bounds__(256, 8)
pull2_kernel(const unsigned* __restrict__ sh, const int* __restrict__ csr,
             const int* __restrict__ node_off, const int* __restrict__ deg,
             const float* __restrict__ dinv, const float* __restrict__ b2,
             float* __restrict__ h2) {
    __shared__ unsigned stage[4][2 * HST];
    int wave = threadIdx.x >> 6;
    int lane = threadIdx.x & 63;
    int h = lane >> 5, l = lane & 31;
    int v = blockIdx.x * 8 + wave * 2 + h;
    int k = l & 15;
    int d = deg[v], o0 = node_off[v];
    unsigned* stg = stage[wave] + h * HST;
    float acc = gather_half(sh, csr, o0, d, stg, l);
    if (l < 16) {
        float dv = dinv[v];
        unsigned ws = sh[(size_t)v * D_H2 + (k >> 1)];
        __half2 ps = *(__half2*)&ws;
        float selfv = (k & 1) ? __high2float(ps) : __low2float(ps);
        float o = dv * (acc + selfv) + b2[k];
        h2[(size_t)v * D_H + k] = fmaxf(o, 0.f);
    }
}

// one block per graph: boundary via binary search on sorted batch, then
// mean-pool h rows and sigmoid(pool @ Wl + bl)
__global__ void pool_head_kernel(const float* __restrict__ h, const int* __restrict__ batch,
                                 const float* __restrict__ Wl, const float* __restrict__ bl,
                                 float* __restrict__ out) {
    int g = blockIdx.x;
    int lo = 0, hi = N_NODES;
    while (lo < hi) { int m = (lo + hi) >> 1; if (batch[m] < g) lo = m + 1; else hi = m; }
    int v0 = lo;
    int lo2 = v0, hi2 = N_NODES;
    while (lo2 < hi2) { int m = (lo2 + hi2) >> 1; if (batch[m] < g + 1) lo2 = m + 1; else hi2 = m; }
    int v1 = lo2;
    int k = threadIdx.x & 15;
    int vi = threadIdx.x >> 4;
    float acc = 0.f;
    for (int v = v0 + vi; v < v1; v += 16) acc += h[v * D_H + k];
    acc += __shfl_xor(acc, 16, 64);
    acc += __shfl_xor(acc, 32, 64);
    __shared__ float sm[4][D_H];
    int lane = threadIdx.x & 63;
    if (lane < 16) sm[threadIdx.x >> 6][k] = acc;
    __syncthreads();
    if (threadIdx.x < 16) {
        float tot = sm[0][k] + sm[1][k] + sm[2][k] + sm[3][k];
        float cntf = (float)(v1 - v0);
        tot /= fmaxf(cntf, 1.0f);
        float p = tot * Wl[k];
        p += __shfl_xor(p, 1, 64);
        p += __shfl_xor(p, 2, 64);
        p += __shfl_xor(p, 4, 64);
        p += __shfl_xor(p, 8, 64);
        if (k == 0) out[g] = 1.0f / (1.0f + expf(-(p + bl[0])));
    }
}

// ---------------- launch ----------------

extern "C" void kernel_launch(void* const* d_in, const int* in_sizes, int n_in,
                              void* d_out, int out_size, void* d_ws, size_t ws_size,
                              hipStream_t stream) {
    const float* x     = (const float*)d_in[0];
    const int*   ei    = (const int*)d_in[1];   // [2, E]: row then col
    const int*   batch = (const int*)d_in[2];
    const float* W1    = (const float*)d_in[3];
    const float* b1    = (const float*)d_in[4];
    const float* W2    = (const float*)d_in[5];
    const float* b2    = (const float*)d_in[6];
    const float* Wl    = (const float*)d_in[7];
    const float* bl    = (const float*)d_in[8];
    float* out = (float*)d_out;

    const int* row = ei;
    const int* col = ei + N_EDGES;

    // workspace layout. Region A is time-shared: {cnt,base} then csr.
    char* wsb = (char*)d_ws;
    size_t o = 0;
    int*      part     = (int*)(wsb + o);      o += (size_t)N_EDGES * 4;      // 12.8 MB
    char*     regionA  = wsb + o;              o += (size_t)N_EDGES * 4;      // 12.8 MB
    int*      cnt      = (int*)regionA;                                       // [NCH][NB]
    int*      base     = (int*)(regionA + (size_t)NCH * NB * 4);              // [NB][NCH]
    int*      csr      = (int*)regionA;                                       // after place
    int*      bcnt     = (int*)(wsb + o);      o += 1024 * 4;
    int*      offs     = (int*)(wsb + o);      o += 1024 * 4;
    int*      node_off = (int*)(wsb + o);      o += 100352 * 4;
    int*      deg      = (int*)(wsb + o);      o += 100352 * 4;
    float*    dinv     = (float*)(wsb + o);    o += 100352 * 4;
    unsigned* xsh      = (unsigned*)(wsb + o); o += (size_t)N_NODES * 4 * 4;    // 1.6 MB
    unsigned* sBh      = (unsigned*)(wsb + o); o += (size_t)N_NODES * D_H2 * 4; // 3.2 MB
    float*    h2       = (float*)(wsb + o);    o += (size_t)N_NODES * D_H * 4;  // 6.4 MB
    int*      ctr      = (int*)(wsb + o);      o += 256;

    // co-residency-sized grid for the fused build kernel (deadlock-safe)
    int maxb = 0;
    hipOccupancyMaxActiveBlocksPerMultiprocessor(&maxb, build_all, 512, 0);
    if (maxb < 1) maxb = 1;
    hipDeviceProp_t props;
    hipGetDeviceProperties(&props, 0);
    int nblk = maxb * props.multiProcessorCount;
    if (nblk > NCH) nblk = NCH;   // no more blocks than max work items
    if (nblk < 1) nblk = 1;

    hipMemsetAsync(ctr, 0, 4, stream);
    build_all<<<nblk, 512, 0, stream>>>(row, col, x, cnt, base, bcnt, offs,
                                        part, csr, node_off, deg, dinv, xsh,
                                        ctr, nblk);

    // ---- layer 1: x-space aggregation, fused @W1 + @W2 epilogue ----
    pull1_kernel<<<N_NODES / 8, 256, 0, stream>>>(xsh, csr, node_off, deg, dinv,
                                                  b1, W1, W2, sBh);
    // ---- layer 2 ----
    pull2_kernel<<<N_NODES / 8, 256, 0, stream>>>(sBh, csr, node_off, deg, dinv,
                                                  b2, h2);
    // ---- pool + head (boundaries via binary search) ----
    pool_head_kernel<<<NUM_GRAPHS, 256, 0, stream>>>(h2, batch, Wl, bl, out);
}

// Round 17
// 134.896 us; speedup vs baseline: 4.1125x; 4.1125x over previous
//
#include <hip/hip_runtime.h>
#include <hip/hip_fp16.h>
#include <math.h>

#define N_NODES    100000
#define N_EDGES    3200000
#define NUM_GRAPHS 512
#define D_IN       7
#define D_H        16
#define D_H2       8                           // half2 words per node row (16 feats)
#define SHIFT      7
#define BWIDTH     128                         // cols per bucket
#define NB         782                         // ceil(N_NODES / BWIDTH)
#define CHUNK      8192
#define NCH        391                         // ceil(N_EDGES / CHUNK)
#define PC         2                           // chunks per thread (colscan)
#define PB         2                           // buckets per thread (place, 512 thr)
#define TPH        36                          // words/feature-word row per half (32+4; %4==0)
#define HST        (8 * TPH)                   // 288 words per half (pull2, 8-word rows)
#define TP1        36
#define HST1       (4 * TP1)                   // 144 words per half (pull1, 4-word rows)

// ---- pass A: per-chunk bucket histograms ----
__global__ void hist_kernel(const int* __restrict__ col, int* __restrict__ cnt) {
    __shared__ int lh[NB];
    int tid = threadIdx.x;
    for (int i = tid; i < NB; i += blockDim.x) lh[i] = 0;
    __syncthreads();
    int e0 = blockIdx.x * CHUNK;
    int e1 = e0 + CHUNK; if (e1 > N_EDGES) e1 = N_EDGES;
    for (int e = e0 + tid; e < e1; e += blockDim.x)
        atomicAdd(&lh[col[e] >> SHIFT], 1);
    __syncthreads();
    int* outp = cnt + (size_t)blockIdx.x * NB;
    for (int i = tid; i < NB; i += blockDim.x) outp[i] = lh[i];
}

// ---- pass B: per-bucket exclusive scan over chunks ----
__global__ void colscan_kernel(const int* __restrict__ cnt, int* __restrict__ base,
                               int* __restrict__ bcnt) {
    __shared__ int ts[256];
    int b = blockIdx.x;
    int tid = threadIdx.x;
    int c0 = tid * PC;
    int vals[PC];
    int sum = 0;
#pragma unroll
    for (int q = 0; q < PC; ++q) {
        int c = c0 + q;
        int v = (c < NCH) ? cnt[(size_t)c * NB + b] : 0;
        vals[q] = v; sum += v;
    }
    ts[tid] = sum;
    __syncthreads();
    for (int st = 1; st < 256; st <<= 1) {
        int v = (tid >= st) ? ts[tid - st] : 0;
        __syncthreads();
        ts[tid] += v;
        __syncthreads();
    }
    int run = ts[tid] - sum;
    int* bp = base + (size_t)b * NCH;
#pragma unroll
    for (int q = 0; q < PC; ++q) {
        int c = c0 + q;
        if (c < NCH) { bp[c] = run; run += vals[q]; }
    }
    if (tid == 0) bcnt[b] = ts[255];
}

// ---- pass C: exclusive scan of bucket totals -> offs ----
__global__ void scan_kernel(const int* __restrict__ bcnt, int* __restrict__ offs) {
    __shared__ int lds[1024];
    int tid = threadIdx.x;
    lds[tid] = (tid < NB) ? bcnt[tid] : 0;
    __syncthreads();
    for (int st = 1; st < 1024; st <<= 1) {
        int v = (tid >= st) ? lds[tid - st] : 0;
        __syncthreads();
        lds[tid] += v;
        __syncthreads();
    }
    if (tid < NB) offs[tid + 1] = lds[tid];
    if (tid == 0) offs[0] = 0;
}

// ---- pass D: place (512 threads, CHUNK=8192, ~76KB LDS) ----
__global__ void place_kernel(const int* __restrict__ row, const int* __restrict__ col,
                             const int* __restrict__ base, const int* __restrict__ offs,
                             int* __restrict__ part) {
    __shared__ int lh[NB];
    __shared__ int sc[NB];
    __shared__ int lb[NB];
    __shared__ int ts[512];
    __shared__ int stage[CHUNK];    // 32 KB
    __shared__ int dstv[CHUNK];     // 32 KB

    int c = blockIdx.x;
    int tid = threadIdx.x;
    int e0 = c * CHUNK;
    int e1 = e0 + CHUNK; if (e1 > N_EDGES) e1 = N_EDGES;
    int n  = e1 - e0;

    for (int i = tid; i < NB; i += blockDim.x) lh[i] = 0;
    __syncthreads();
    for (int e = e0 + tid; e < e1; e += blockDim.x)
        atomicAdd(&lh[col[e] >> SHIFT], 1);
    __syncthreads();
    int b0 = tid * PB;
    int vals[PB];
    int sum = 0;
#pragma unroll
    for (int q = 0; q < PB; ++q) {
        int b = b0 + q;
        int v = (b < NB) ? lh[b] : 0;
        vals[q] = v; sum += v;
    }
    ts[tid] = sum;
    __syncthreads();
    for (int st = 1; st < 512; st <<= 1) {
        int v = (tid >= st) ? ts[tid - st] : 0;
        __syncthreads();
        ts[tid] += v;
        __syncthreads();
    }
    int run = ts[tid] - sum;
#pragma unroll
    for (int q = 0; q < PB; ++q) {
        int b = b0 + q;
        if (b < NB) {
            sc[b] = run;
            lb[b] = offs[b] + base[(size_t)b * NCH + c];
            run += vals[q];
            lh[b] = 0;
        }
    }
    __syncthreads();
    for (int e = e0 + tid; e < e1; e += blockDim.x) {
        int cc = col[e];
        int b = cc >> SHIFT;
        int rank = atomicAdd(&lh[b], 1);
        int loc = sc[b] + rank;
        stage[loc] = (row[e] << SHIFT) | (cc & (BWIDTH - 1));
        dstv[loc]  = lb[b] + rank;
    }
    __syncthreads();
    for (int i = tid; i < n; i += blockDim.x)
        part[dstv[i]] = stage[i];
}

// ---- pass E: per-bucket CSR build + node_off/deg/dinv + fused xs pack ----
__global__ void csr_kernel(const int* __restrict__ part, const int* __restrict__ offs,
                           const float* __restrict__ x,
                           int* __restrict__ csr, int* __restrict__ node_off,
                           int* __restrict__ deg, float* __restrict__ dinv,
                           unsigned* __restrict__ xsh) {
    __shared__ int cnt[BWIDTH];
    __shared__ int scn[BWIDTH];
    __shared__ int cur[BWIDTH];
    int b = blockIdx.x;
    int o0 = offs[b], o1 = offs[b + 1];
    if (threadIdx.x < BWIDTH) cnt[threadIdx.x] = 0;
    __syncthreads();
    for (int j = o0 + threadIdx.x; j < o1; j += blockDim.x)
        atomicAdd(&cnt[part[j] & (BWIDTH - 1)], 1);
    __syncthreads();
    if (threadIdx.x < BWIDTH) scn[threadIdx.x] = cnt[threadIdx.x];
    __syncthreads();
    for (int st = 1; st < BWIDTH; st <<= 1) {
        int v = 0;
        if (threadIdx.x < BWIDTH && threadIdx.x >= st) v = scn[threadIdx.x - st];
        __syncthreads();
        if (threadIdx.x < BWIDTH) scn[threadIdx.x] += v;
        __syncthreads();
    }
    if (threadIdx.x < BWIDTH) {
        int excl = scn[threadIdx.x] - cnt[threadIdx.x];
        cur[threadIdx.x] = excl;
        int c = b * BWIDTH + threadIdx.x;
        if (c < N_NODES) {
            node_off[c] = o0 + excl;
            deg[c] = cnt[threadIdx.x];
            float dv = rsqrtf((float)cnt[threadIdx.x] + 1.0f);   // +1 self-loop
            dinv[c] = dv;
            // fused xs pack: xs[c,:] = dv * x[c,:], 7 feats + 0-pad, half2 x4
            float xv[8];
#pragma unroll
            for (int j = 0; j < D_IN; ++j) xv[j] = x[(size_t)c * D_IN + j] * dv;
            xv[7] = 0.f;
#pragma unroll
            for (int w = 0; w < 4; ++w) {
                __half2 p = __floats2half2_rn(xv[2 * w], xv[2 * w + 1]);
                xsh[(size_t)c * 4 + w] = *(unsigned*)&p;
            }
        }
    }
    __syncthreads();
    for (int j = o0 + threadIdx.x; j < o1; j += blockDim.x) {
        int e = part[j];
        int l = e & (BWIDTH - 1);
        int pos = atomicAdd(&cur[l], 1);
        csr[o0 + pos] = e >> SHIFT;
    }
}

// ---- pull1: 2 nodes/wave, 16B x-rows, post-aggregation @W1 then @W2 ----
__global__ void __launch_bounds__(256, 8)
pull1_kernel(const unsigned* __restrict__ xsh, const int* __restrict__ csr,
             const int* __restrict__ node_off, const int* __restrict__ deg,
             const float* __restrict__ dinv, const float* __restrict__ b1,
             const float* __restrict__ W1, const float* __restrict__ W2,
             unsigned* __restrict__ s2h) {
    __shared__ unsigned stage[4][2 * HST1];   // 4608 B
    __shared__ float aggrow[4][2][8];
    __shared__ float hrow[4][2][D_H];
    int wave = threadIdx.x >> 6;
    int lane = threadIdx.x & 63;
    int h = lane >> 5, l = lane & 31;
    int v = blockIdx.x * 8 + wave * 2 + h;
    int k = l & 15;
    float w1c[D_IN];
#pragma unroll
    for (int j = 0; j < D_IN; ++j) w1c[j] = W1[j * D_H + k];
    float w2c[D_H];
#pragma unroll
    for (int j = 0; j < D_H; ++j) w2c[j] = W2[j * D_H + k];
    int d = deg[v], o0 = node_off[v];
    unsigned* stg = stage[wave] + h * HST1;
    int rg = l >> 3, p = l & 7;
    int w = p >> 1;
    bool hi = (p & 1);
    const uint4* rp = (const uint4*)(stg + w * TP1 + rg * 8);
    float acc = 0.f;
    for (int base = 0; base < d; base += 32) {
        int j = base + l;
        uint4 a = make_uint4(0u, 0u, 0u, 0u);
        if (j < d) {
            int r = __builtin_nontemporal_load(&csr[o0 + j]);
            a = *(const uint4*)(xsh + (size_t)r * 4);
        }
        asm volatile("s_waitcnt lgkmcnt(0)" ::: "memory");
        stg[0 * TP1 + l] = a.x;
        stg[1 * TP1 + l] = a.y;
        stg[2 * TP1 + l] = a.z;
        stg[3 * TP1 + l] = a.w;
        asm volatile("s_waitcnt lgkmcnt(0)" ::: "memory");
        uint4 q0 = rp[0], q1 = rp[1];
        unsigned ws[8] = { q0.x, q0.y, q0.z, q0.w, q1.x, q1.y, q1.z, q1.w };
#pragma unroll
        for (int i = 0; i < 8; ++i) {
            __half2 ph = *(__half2*)&ws[i];
            acc += hi ? __high2float(ph) : __low2float(ph);
        }
    }
    acc += __shfl_xor(acc, 8, 64);
    acc += __shfl_xor(acc, 16, 64);   // all 32 lanes: agg for x-feature p
    float dv = dinv[v];
    if (l < 8) aggrow[wave][h][l] = acc;
    asm volatile("s_waitcnt lgkmcnt(0)" ::: "memory");
    uint4 sx = *(const uint4*)(xsh + (size_t)v * 4);
    unsigned sxw[4] = { sx.x, sx.y, sx.z, sx.w };
    const float* ag = aggrow[wave][h];
    float hv = b1[k];
#pragma unroll
    for (int j = 0; j < D_IN; ++j) {
        __half2 ph = *(__half2*)&sxw[j >> 1];
        float xsv = (j & 1) ? __high2float(ph) : __low2float(ph);
        hv += dv * (ag[j] + xsv) * w1c[j];
    }
    hv = fmaxf(hv, 0.f);
    if (l < 16) hrow[wave][h][k] = hv;
    asm volatile("s_waitcnt lgkmcnt(0)" ::: "memory");
    const float4* hp = (const float4*)hrow[wave][h];
    float4 h0 = hp[0], h1 = hp[1], h2 = hp[2], h3 = hp[3];
    float a2 = h0.x * w2c[0] + h0.y * w2c[1] + h0.z * w2c[2] + h0.w * w2c[3]
             + h1.x * w2c[4] + h1.y * w2c[5] + h1.z * w2c[6] + h1.w * w2c[7]
             + h2.x * w2c[8] + h2.y * w2c[9] + h2.z * w2c[10] + h2.w * w2c[11]
             + h3.x * w2c[12] + h3.y * w2c[13] + h3.z * w2c[14] + h3.w * w2c[15];
    a2 *= dv;
    float a2hi = __shfl_xor(a2, 1, 64);
    if (l < 16 && (k & 1) == 0) {
        __half2 pq = __floats2half2_rn(a2, a2hi);
        s2h[(size_t)v * D_H2 + (k >> 1)] = *(unsigned*)&pq;
    }
}

// ---- pull2 gather core: 2 nodes/wave, 32B s2-rows ----
__device__ __forceinline__ float gather_half(const unsigned* __restrict__ sh,
                                             const int* __restrict__ csr,
                                             int o0, int d, unsigned* stg, int l) {
    int g = l >> 4, k = l & 15;
    const uint4* rp = (const uint4*)(stg + (k >> 1) * TPH + g * 16);
    bool hi = (k & 1);
    float acc = 0.f;
    for (int base = 0; base < d; base += 32) {
        int j = base + l;
        uint4 a = make_uint4(0u, 0u, 0u, 0u), b = make_uint4(0u, 0u, 0u, 0u);
        if (j < d) {
            int r = __builtin_nontemporal_load(&csr[o0 + j]);
            const uint4* sp = (const uint4*)(sh + (size_t)r * D_H2);
            a = sp[0];
            b = sp[1];
        }
        asm volatile("s_waitcnt lgkmcnt(0)" ::: "memory");
        stg[0 * TPH + l] = a.x;
        stg[1 * TPH + l] = a.y;
        stg[2 * TPH + l] = a.z;
        stg[3 * TPH + l] = a.w;
        stg[4 * TPH + l] = b.x;
        stg[5 * TPH + l] = b.y;
        stg[6 * TPH + l] = b.z;
        stg[7 * TPH + l] = b.w;
        asm volatile("s_waitcnt lgkmcnt(0)" ::: "memory");
        uint4 q0 = rp[0], q1 = rp[1], q2 = rp[2], q3 = rp[3];
        unsigned ws[16] = { q0.x, q0.y, q0.z, q0.w, q1.x, q1.y, q1.z, q1.w,
                            q2.x, q2.y, q2.z, q2.w, q3.x, q3.y, q3.z, q3.w };
#pragma unroll
        for (int i = 0; i < 16; ++i) {
            __half2 p = *(__half2*)&ws[i];
            acc += hi ? __high2float(p) : __low2float(p);
        }
    }
    acc += __shfl_xor(acc, 16, 64);
    return acc;
}

// layer-2 pull (2 nodes/wave): h2 = relu(dinv*(gather+self)+b2), fp32 out
__global__ void __launch_bounds__(256, 8)
pull2_kernel(const unsigned* __restrict__ sh, const int* __restrict__ csr,
             const int* __restrict__ node_off, const int* __restrict__ deg,
             const float* __restrict__ dinv, const float* __restrict__ b2,
             float* __restrict__ h2) {
    __shared__ unsigned stage[4][2 * HST];
    int wave = threadIdx.x >> 6;
    int lane = threadIdx.x & 63;
    int h = lane >> 5, l = lane & 31;
    int v = blockIdx.x * 8 + wave * 2 + h;
    int k = l & 15;
    int d = deg[v], o0 = node_off[v];
    unsigned* stg = stage[wave] + h * HST;
    float acc = gather_half(sh, csr, o0, d, stg, l);
    if (l < 16) {
        float dv = dinv[v];
        unsigned ws = sh[(size_t)v * D_H2 + (k >> 1)];
        __half2 ps = *(__half2*)&ws;
        float selfv = (k & 1) ? __high2float(ps) : __low2float(ps);
        float o = dv * (acc + selfv) + b2[k];
        h2[(size_t)v * D_H + k] = fmaxf(o, 0.f);
    }
}

// one block per graph: boundaries via binary search on sorted batch, then
// mean-pool h rows and sigmoid(pool @ Wl + bl)
__global__ void pool_head_kernel(const float* __restrict__ h, const int* __restrict__ batch,
                                 const float* __restrict__ Wl, const float* __restrict__ bl,
                                 float* __restrict__ out) {
    int g = blockIdx.x;
    int lo = 0, hi = N_NODES;
    while (lo < hi) { int m = (lo + hi) >> 1; if (batch[m] < g) lo = m + 1; else hi = m; }
    int v0 = lo;
    int lo2 = v0, hi2 = N_NODES;
    while (lo2 < hi2) { int m = (lo2 + hi2) >> 1; if (batch[m] < g + 1) lo2 = m + 1; else hi2 = m; }
    int v1 = lo2;
    int k = threadIdx.x & 15;
    int vi = threadIdx.x >> 4;
    float acc = 0.f;
    for (int v = v0 + vi; v < v1; v += 16) acc += h[v * D_H + k];
    acc += __shfl_xor(acc, 16, 64);
    acc += __shfl_xor(acc, 32, 64);
    __shared__ float sm[4][D_H];
    int lane = threadIdx.x & 63;
    if (lane < 16) sm[threadIdx.x >> 6][k] = acc;
    __syncthreads();
    if (threadIdx.x < 16) {
        float tot = sm[0][k] + sm[1][k] + sm[2][k] + sm[3][k];
        float cntf = (float)(v1 - v0);
        tot /= fmaxf(cntf, 1.0f);
        float p = tot * Wl[k];
        p += __shfl_xor(p, 1, 64);
        p += __shfl_xor(p, 2, 64);
        p += __shfl_xor(p, 4, 64);
        p += __shfl_xor(p, 8, 64);
        if (k == 0) out[g] = 1.0f / (1.0f + expf(-(p + bl[0])));
    }
}

// ---------------- launch ----------------

extern "C" void kernel_launch(void* const* d_in, const int* in_sizes, int n_in,
                              void* d_out, int out_size, void* d_ws, size_t ws_size,
                              hipStream_t stream) {
    const float* x     = (const float*)d_in[0];
    const int*   ei    = (const int*)d_in[1];   // [2, E]: row then col
    const int*   batch = (const int*)d_in[2];
    const float* W1    = (const float*)d_in[3];
    const float* b1    = (const float*)d_in[4];
    const float* W2    = (const float*)d_in[5];
    const float* b2    = (const float*)d_in[6];
    const float* Wl    = (const float*)d_in[7];
    const float* bl    = (const float*)d_in[8];
    float* out = (float*)d_out;

    const int* row = ei;
    const int* col = ei + N_EDGES;

    // workspace layout. Region A is time-shared: {cnt,base} then csr.
    char* wsb = (char*)d_ws;
    size_t o = 0;
    int*      part     = (int*)(wsb + o);      o += (size_t)N_EDGES * 4;      // 12.8 MB
    char*     regionA  = wsb + o;              o += (size_t)N_EDGES * 4;      // 12.8 MB
    int*      cnt      = (int*)regionA;                                       // [NCH][NB]
    int*      base     = (int*)(regionA + (size_t)NCH * NB * 4);              // [NB][NCH]
    int*      csr      = (int*)regionA;                                       // after place
    int*      bcnt     = (int*)(wsb + o);      o += 1024 * 4;
    int*      offs     = (int*)(wsb + o);      o += 1024 * 4;
    int*      node_off = (int*)(wsb + o);      o += 100352 * 4;
    int*      deg      = (int*)(wsb + o);      o += 100352 * 4;
    float*    dinv     = (float*)(wsb + o);    o += 100352 * 4;
    unsigned* xsh      = (unsigned*)(wsb + o); o += (size_t)N_NODES * 4 * 4;    // 1.6 MB
    unsigned* sBh      = (unsigned*)(wsb + o); o += (size_t)N_NODES * D_H2 * 4; // 3.2 MB
    float*    h2       = (float*)(wsb + o);    o += (size_t)N_NODES * D_H * 4;  // 6.4 MB

    const int B = 256;

    // ---- build CSR via deterministic two-level scan (no global cursor atomics) ----
    hist_kernel<<<NCH, 512, 0, stream>>>(col, cnt);
    colscan_kernel<<<NB, B, 0, stream>>>(cnt, base, bcnt);
    scan_kernel<<<1, 1024, 0, stream>>>(bcnt, offs);
    place_kernel<<<NCH, 512, 0, stream>>>(row, col, base, offs, part);
    csr_kernel<<<NB, 512, 0, stream>>>(part, offs, x, csr, node_off, deg, dinv, xsh);

    // ---- layer 1: x-space aggregation, fused @W1 + @W2 epilogue ----
    pull1_kernel<<<N_NODES / 8, B, 0, stream>>>(xsh, csr, node_off, deg, dinv,
                                                b1, W1, W2, sBh);
    // ---- layer 2 ----
    pull2_kernel<<<N_NODES / 8, B, 0, stream>>>(sBh, csr, node_off, deg, dinv,
                                                b2, h2);
    // ---- pool + head (boundaries via binary search) ----
    pool_head_kernel<<<NUM_GRAPHS, B, 0, stream>>>(h2, batch, Wl, bl, out);
}